// Round 4
// baseline (416.631 us; speedup 1.0000x reference)
//
#include <hip/hip_runtime.h>

typedef __attribute__((ext_vector_type(8))) short short8;
typedef __attribute__((ext_vector_type(4))) float f32x4;
typedef __attribute__((ext_vector_type(4))) unsigned short us4;
typedef __attribute__((ext_vector_type(4))) float float4v;

#define GLB_PTR(p) ((const __attribute__((address_space(1))) void*)(p))
#define LDS_PTR(p) ((__attribute__((address_space(3))) void*)(p))

__device__ __forceinline__ unsigned short f2bf(float f) {
  unsigned int u = __float_as_uint(f);
  u += 0x7FFF + ((u >> 16) & 1);   // round-to-nearest-even
  return (unsigned short)(u >> 16);
}

// ---------------- fp32 -> bf16 convert (vectorized) ----------------
__global__ void cvt_kernel(const float* __restrict__ in, unsigned short* __restrict__ out, int n4) {
  int i = blockIdx.x * blockDim.x + threadIdx.x;
  int stride = gridDim.x * blockDim.x;
  for (; i < n4; i += stride) {
    float4v v = *(const float4v*)(in + (size_t)i * 4);
    us4 o;
    o[0] = f2bf(v[0]); o[1] = f2bf(v[1]); o[2] = f2bf(v[2]); o[3] = f2bf(v[3]);
    *(us4*)(out + (size_t)i * 4) = o;
  }
}

// 4 weight matrices in one launch (blockIdx.y selects tensor)
__global__ void cvt4_kernel(const float* __restrict__ w0, const float* __restrict__ w1,
                            const float* __restrict__ w2, const float* __restrict__ w3,
                            unsigned short* __restrict__ o0, unsigned short* __restrict__ o1,
                            unsigned short* __restrict__ o2, unsigned short* __restrict__ o3,
                            int n4) {
  const float* in = blockIdx.y == 0 ? w0 : blockIdx.y == 1 ? w1 : blockIdx.y == 2 ? w2 : w3;
  unsigned short* out = blockIdx.y == 0 ? o0 : blockIdx.y == 1 ? o1 : blockIdx.y == 2 ? o2 : o3;
  int i = blockIdx.x * blockDim.x + threadIdx.x;
  int stride = gridDim.x * blockDim.x;
  for (; i < n4; i += stride) {
    float4v v = *(const float4v*)(in + (size_t)i * 4);
    us4 o;
    o[0] = f2bf(v[0]); o[1] = f2bf(v[1]); o[2] = f2bf(v[2]); o[3] = f2bf(v[3]);
    *(us4*)(out + (size_t)i * 4) = o;
  }
}

// ---------------- big bf16 GEMM: C[16384,1536] = A[16384,1536] * B[1536,1536]^T ----------------
// 256x128 block tile, BK=32, 4 waves (2Mx2N), wave tile 128x64 (8x4 fragments).
// Depth-3 LDS pipeline + cross-iteration fragment double-buffer:
//   iter kt: vmcnt(6) [tile kt+1 staged] + lgkmcnt(0) [own reads of buf kt done]
//            -> ONE barrier -> stage kt+3 into freed buf -> ds_read frags[kt+1]
//            -> MFMA frags[kt] (compiler interleaves reads & MFMA; no drain between).
// XOR granule swizzle perm = lg ^ ((row>>1)&3), applied on BOTH source and read (involution).
// MODE 0: C bf16.  MODE 1: C fp32 = acc + bias[n] + resid[m,n].
template<int MODE>
__global__ __launch_bounds__(256, 2) void gemm_big(
    const unsigned short* __restrict__ A,
    const unsigned short* __restrict__ B,
    unsigned short* __restrict__ Cb,
    float* __restrict__ Cf,
    const float* __restrict__ bias,
    const float* __restrict__ resid) {
  constexpr int K = 1536, N = 1536, BK = 32, NKT = K / BK;  // 48 K-tiles (even)
  __shared__ unsigned short As[3][256 * 32];
  __shared__ unsigned short Bs[3][128 * 32];

  // XCD-chunked swizzle: 768 blocks -> 96/XCD = 8 m-tiles x 12 n-tiles, n fastest
  const int bid = blockIdx.x;
  const int xcd = bid & 7, idx = bid >> 3;
  const int m0 = (xcd * 8 + idx / 12) * 256;
  const int n0 = (idx % 12) * 128;

  const int t = threadIdx.x;
  const int w = t >> 6, l = t & 63, lr = l & 15, lg = l >> 4;
  const int wr = w >> 1, wc = w & 1;
  const int ga = lg ^ ((lr >> 1) & 3);   // read granule: covers all 8 16B-slots 2x per 16 lanes

  // staging source: thread t -> linear LDS byte t*16 (+ i*4096); row = srow + i*64
  const int srow = t >> 2;
  const int sg = (t & 3) ^ ((srow >> 1) & 3);   // inverse (involution) of read swizzle
  const unsigned short* aSrc = A + (size_t)(m0 + srow) * K + sg * 8;
  const unsigned short* bSrc = B + (size_t)(n0 + srow) * K + sg * 8;

  f32x4 acc[8][4] = {};

  auto stage = [&](int buf, int kt) {
    const int k0 = kt * BK;
    unsigned short* AsW = &As[buf][0] + w * 512;   // wave-uniform base (w*1024 bytes)
    unsigned short* BsW = &Bs[buf][0] + w * 512;
#pragma unroll
    for (int i = 0; i < 4; ++i)
      __builtin_amdgcn_global_load_lds(GLB_PTR(aSrc + (size_t)(i * 64) * K + k0), LDS_PTR(AsW + i * 2048), 16, 0, 0);
#pragma unroll
    for (int i = 0; i < 2; ++i)
      __builtin_amdgcn_global_load_lds(GLB_PTR(bSrc + (size_t)(i * 64) * K + k0), LDS_PTR(BsW + i * 2048), 16, 0, 0);
  };

  auto loadfrags = [&](int buf, short8* af, short8* bfv) {
    const unsigned short* Asb = &As[buf][0];
    const unsigned short* Bsb = &Bs[buf][0];
#pragma unroll
    for (int i = 0; i < 8; ++i)
      af[i] = *(const short8*)(Asb + (wr * 128 + i * 16 + lr) * 32 + ga * 8);
#pragma unroll
    for (int j = 0; j < 4; ++j)
      bfv[j] = *(const short8*)(Bsb + (wc * 64 + j * 16 + lr) * 32 + ga * 8);
  };

  auto mfma_all = [&](short8* af, short8* bfv) {
#pragma unroll
    for (int i = 0; i < 8; ++i)
#pragma unroll
      for (int j = 0; j < 4; ++j)
        acc[i][j] = __builtin_amdgcn_mfma_f32_16x16x32_bf16(af[i], bfv[j], acc[i][j], 0, 0, 0);
  };

  short8 afA[8], bfA[4], afB[8], bfB[4];

  // iteration body: consumes (caf,cbf) = frags[kt]; loads (naf,nbf) = frags[kt+1]
  auto iter = [&](int kt, short8* caf, short8* cbf, short8* naf, short8* nbf) {
    if (kt < NKT - 1) {
      if (kt < NKT - 2) asm volatile("s_waitcnt vmcnt(6)" ::: "memory");   // tile kt+1 landed (own)
      else              asm volatile("s_waitcnt vmcnt(0)" ::: "memory");
    }
    asm volatile("s_waitcnt lgkmcnt(0)" ::: "memory");   // own reads of buf kt%3 drained
    __builtin_amdgcn_s_barrier();                        // join: kt+1 valid, kt%3 free
    if (kt + 3 < NKT) stage(kt % 3, kt + 3);             // overwrite freed buffer
    if (kt + 1 < NKT) loadfrags((kt + 1) % 3, naf, nbf); // reads overlap MFMA below
    __builtin_amdgcn_s_setprio(1);
    mfma_all(caf, cbf);
    __builtin_amdgcn_s_setprio(0);
  };

  // prologue: 3 K-tiles in flight (18 loads/wave); pre-read frags[0]
  stage(0, 0); stage(1, 1); stage(2, 2);
  asm volatile("s_waitcnt vmcnt(12)" ::: "memory");      // tile 0 landed
  __builtin_amdgcn_s_barrier();
  loadfrags(0, afA, bfA);

  for (int kt = 0; kt < NKT; kt += 2) {
    iter(kt,     afA, bfA, afB, bfB);
    iter(kt + 1, afB, bfB, afA, bfA);
  }

#pragma unroll
  for (int i = 0; i < 8; ++i) {
    const int rb = m0 + wr * 128 + i * 16 + lg * 4;
#pragma unroll
    for (int j = 0; j < 4; ++j) {
      const int col = n0 + wc * 64 + j * 16 + lr;
#pragma unroll
      for (int r = 0; r < 4; ++r) {
        size_t o = (size_t)(rb + r) * N + col;
        if (MODE == 0) Cb[o] = f2bf(acc[i][j][r]);
        else           Cf[o] = acc[i][j][r] + bias[col] + resid[o];
      }
    }
  }
}

// ---------------- K+V projection (small M): 128x128 tile, merged into one launch ----------------
__global__ __launch_bounds__(256) void gemm_kv(
    const unsigned short* __restrict__ A,    // EHSb [616,1536]
    const unsigned short* __restrict__ Bk,
    const unsigned short* __restrict__ Bv,
    unsigned short* __restrict__ Ck,
    unsigned short* __restrict__ Cv) {
  constexpr int K = 1536, N = 1536, Mc = 615;
  __shared__ unsigned short As[128 * 32];
  __shared__ unsigned short Bs[128 * 32];
  const unsigned short* B = blockIdx.y < 12 ? Bk : Bv;
  unsigned short* C = blockIdx.y < 12 ? Ck : Cv;
  const int m0 = blockIdx.x * 128, n0 = (blockIdx.y % 12) * 128;
  const int t = threadIdx.x;
  const int w = t >> 6, l = t & 63, lr = l & 15, lg = l >> 4;
  const int wr = w >> 1, wc = w & 1;
  const int srow = t >> 2, scol = (t & 3) * 8;

  f32x4 acc[4][4] = {};
  unsigned short* AsW = As + w * 512;
  unsigned short* BsW = Bs + w * 512;
  long ar0 = m0 + srow;       if (ar0 > Mc) ar0 = Mc;
  long ar1 = m0 + srow + 64;  if (ar1 > Mc) ar1 = Mc;

  for (int k0 = 0; k0 < K; k0 += 32) {
    __builtin_amdgcn_global_load_lds(GLB_PTR(A + ar0 * (long)K + k0 + scol), LDS_PTR(AsW),        16, 0, 0);
    __builtin_amdgcn_global_load_lds(GLB_PTR(A + ar1 * (long)K + k0 + scol), LDS_PTR(AsW + 2048), 16, 0, 0);
    __builtin_amdgcn_global_load_lds(GLB_PTR(B + (long)(n0 + srow) * K + k0 + scol),      LDS_PTR(BsW),        16, 0, 0);
    __builtin_amdgcn_global_load_lds(GLB_PTR(B + (long)(n0 + srow + 64) * K + k0 + scol), LDS_PTR(BsW + 2048), 16, 0, 0);
    __syncthreads();

    short8 af[4], bfv[4];
#pragma unroll
    for (int i = 0; i < 4; ++i) {
      af[i]  = *(const short8*)(As + (wr * 64 + i * 16 + lr) * 32 + lg * 8);
      bfv[i] = *(const short8*)(Bs + (wc * 64 + i * 16 + lr) * 32 + lg * 8);
    }
#pragma unroll
    for (int i = 0; i < 4; ++i)
#pragma unroll
      for (int j = 0; j < 4; ++j)
        acc[i][j] = __builtin_amdgcn_mfma_f32_16x16x32_bf16(af[i], bfv[j], acc[i][j], 0, 0, 0);
    __syncthreads();
  }

#pragma unroll
  for (int i = 0; i < 4; ++i) {
    int rb = m0 + wr * 64 + i * 16 + lg * 4;
#pragma unroll
    for (int j = 0; j < 4; ++j) {
      int col = n0 + wc * 64 + j * 16 + lr;
#pragma unroll
      for (int r = 0; r < 4; ++r)
        C[(long)(rb + r) * N + col] = f2bf(acc[i][j][r]);
    }
  }
}

// ---------------- V transpose: Vb[(c*154+e), h*64+d] -> Vt[c][h][d][e(160, zero-pad)] ----------------
__global__ void vtrans(const unsigned short* __restrict__ Vb, unsigned short* __restrict__ Vt) {
  int c = blockIdx.x / 24, h = blockIdx.x % 24;
  for (int idx = threadIdx.x; idx < 64 * 160; idx += blockDim.x) {
    int d = idx & 63, e = idx >> 6;
    unsigned short v = 0;
    if (e < 154) v = Vb[(long)(c * 154 + e) * 1536 + h * 64 + d];
    Vt[((long)((c * 24 + h) * 64 + d)) * 160 + e] = v;
  }
}

// ---------------- fused cross-component attention ----------------
__global__ __launch_bounds__(256) void attn_kernel(
    const unsigned short* __restrict__ Qb,   // [4*4096, 1536]
    const unsigned short* __restrict__ Kb,   // [640, 1536]; rows c*154+e
    const unsigned short* __restrict__ Vt,   // [4][24][64][160]
    const float* __restrict__ temp,
    unsigned short* __restrict__ Ob) {       // [4*4096, 1536]
  __shared__ unsigned short P[4][4][16][160];  // [wave][c][s][e] bf16 weights
  const int h = blockIdx.y, sb = blockIdx.x;
  const int t = threadIdx.x, w = t >> 6, l = t & 63, lr = l & 15, lg = l >> 4;
  const int s0 = sb * 64 + w * 16;
  const float sc = 1.0f / (temp[0] + 1e-8f);

  short8 qf[4][2];
#pragma unroll
  for (int c = 0; c < 4; ++c)
#pragma unroll
    for (int kt = 0; kt < 2; ++kt)
      qf[c][kt] = *(const short8*)(Qb + (long)(c * 4096 + s0 + lr) * 1536 + h * 64 + kt * 32 + lg * 8);

  for (int et = 0; et < 10; ++et) {
    f32x4 sa[4] = {};
#pragma unroll
    for (int c = 0; c < 4; ++c)
#pragma unroll
      for (int kt = 0; kt < 2; ++kt) {
        short8 kf = *(const short8*)(Kb + (long)(c * 154 + et * 16 + lr) * 1536 + h * 64 + kt * 32 + lg * 8);
        sa[c] = __builtin_amdgcn_mfma_f32_16x16x32_bf16(kf, qf[c][kt], sa[c], 0, 0, 0);
      }
    float wv[4][4];
#pragma unroll
    for (int r = 0; r < 4; ++r) {
      float x0 = sa[0][r] * sc, x1 = sa[1][r] * sc, x2 = sa[2][r] * sc, x3 = sa[3][r] * sc;
      float m = fmaxf(fmaxf(x0, x1), fmaxf(x2, x3));
      float e0 = __expf(x0 - m), e1 = __expf(x1 - m), e2 = __expf(x2 - m), e3 = __expf(x3 - m);
      float inv = 1.0f / (e0 + e1 + e2 + e3);
      wv[0][r] = e0 * inv; wv[1][r] = e1 * inv; wv[2][r] = e2 * inv; wv[3][r] = e3 * inv;
    }
#pragma unroll
    for (int c = 0; c < 4; ++c) {
      us4 pk;
      pk[0] = f2bf(wv[c][0]); pk[1] = f2bf(wv[c][1]); pk[2] = f2bf(wv[c][2]); pk[3] = f2bf(wv[c][3]);
      *(us4*)&P[w][c][lr][et * 16 + lg * 4] = pk;
    }
  }
  __syncthreads();

  f32x4 o[4][4] = {};
#pragma unroll
  for (int c = 0; c < 4; ++c)
    for (int ks = 0; ks < 5; ++ks) {
      short8 pf = *(const short8*)&P[w][c][lr][ks * 32 + lg * 8];
#pragma unroll
      for (int nt = 0; nt < 4; ++nt) {
        short8 vf = *(const short8*)(Vt + (long)((c * 24 + h) * 64 + nt * 16 + lr) * 160 + ks * 32 + lg * 8);
        o[c][nt] = __builtin_amdgcn_mfma_f32_16x16x32_bf16(pf, vf, o[c][nt], 0, 0, 0);
      }
    }

#pragma unroll
  for (int c = 0; c < 4; ++c)
#pragma unroll
    for (int nt = 0; nt < 4; ++nt)
#pragma unroll
      for (int r = 0; r < 4; ++r)
        Ob[(long)(c * 4096 + s0 + lg * 4 + r) * 1536 + h * 64 + nt * 16 + lr] = f2bf(o[c][nt][r]);
}

extern "C" void kernel_launch(void* const* d_in, const int* in_sizes, int n_in,
                              void* d_out, int out_size, void* d_ws, size_t ws_size,
                              hipStream_t stream) {
  (void)in_sizes; (void)n_in; (void)out_size; (void)ws_size;
  const float* HS  = (const float*)d_in[0];
  const float* EHS = (const float*)d_in[1];
  const float* TMP = (const float*)d_in[2];
  const float* Wq  = (const float*)d_in[3];
  const float* Wk  = (const float*)d_in[4];
  const float* Wv  = (const float*)d_in[5];
  const float* Wo  = (const float*)d_in[6];
  const float* bo  = (const float*)d_in[7];

  char* ws = (char*)d_ws;
  size_t off = 0;
  unsigned short* HSb  = (unsigned short*)(ws + off); off += (size_t)16384 * 1536 * 2;  // reused as Ob
  unsigned short* Ob   = HSb;
  unsigned short* EHSb = (unsigned short*)(ws + off); off += (size_t)616 * 1536 * 2;
  unsigned short* Wqb  = (unsigned short*)(ws + off); off += (size_t)1536 * 1536 * 2;
  unsigned short* Wkb  = (unsigned short*)(ws + off); off += (size_t)1536 * 1536 * 2;
  unsigned short* Wvb  = (unsigned short*)(ws + off); off += (size_t)1536 * 1536 * 2;
  unsigned short* Wob  = (unsigned short*)(ws + off); off += (size_t)1536 * 1536 * 2;
  unsigned short* Kb   = (unsigned short*)(ws + off); off += (size_t)640 * 1536 * 2;
  unsigned short* Vb   = (unsigned short*)(ws + off); off += (size_t)640 * 1536 * 2;
  unsigned short* Vt   = (unsigned short*)(ws + off); off += (size_t)4 * 24 * 64 * 160 * 2;
  unsigned short* Qb   = (unsigned short*)d_out;  // bf16 scratch; final GEMM overwrites d_out fully

  cvt_kernel<<<2048, 256, 0, stream>>>(HS,  HSb,  16384 * 1536 / 4);
  cvt_kernel<<<512,  256, 0, stream>>>(EHS, EHSb, 616 * 1536 / 4);
  cvt4_kernel<<<dim3(576, 4), 256, 0, stream>>>(Wq, Wk, Wv, Wo, Wqb, Wkb, Wvb, Wob, 1536 * 1536 / 4);

  gemm_big<0><<<768, 256, 0, stream>>>(HSb, Wqb, Qb, nullptr, nullptr, nullptr);
  gemm_kv<<<dim3(5, 24), 256, 0, stream>>>(EHSb, Wkb, Wvb, Kb, Vb);

  vtrans<<<96, 256, 0, stream>>>(Vb, Vt);

  attn_kernel<<<dim3(64, 24), 256, 0, stream>>>(Qb, Kb, Vt, TMP, Ob);

  gemm_big<1><<<768, 256, 0, stream>>>(Ob, Wob, nullptr, (float*)d_out, bo, HS);
}

// Round 6
// 413.363 us; speedup vs baseline: 1.0079x; 1.0079x over previous
//
#include <hip/hip_runtime.h>

typedef __attribute__((ext_vector_type(8))) short short8;
typedef __attribute__((ext_vector_type(4))) float f32x4;
typedef __attribute__((ext_vector_type(4))) unsigned short us4;
typedef __attribute__((ext_vector_type(4))) float float4v;

#define GLB_PTR(p) ((const __attribute__((address_space(1))) void*)(p))
#define LDS_PTR(p) ((__attribute__((address_space(3))) void*)(p))

__device__ __forceinline__ unsigned short f2bf(float f) {
  unsigned int u = __float_as_uint(f);
  u += 0x7FFF + ((u >> 16) & 1);   // round-to-nearest-even
  return (unsigned short)(u >> 16);
}

// ---------------- fp32 -> bf16 convert (vectorized) ----------------
__global__ void cvt_kernel(const float* __restrict__ in, unsigned short* __restrict__ out, int n4) {
  int i = blockIdx.x * blockDim.x + threadIdx.x;
  int stride = gridDim.x * blockDim.x;
  for (; i < n4; i += stride) {
    float4v v = *(const float4v*)(in + (size_t)i * 4);
    us4 o;
    o[0] = f2bf(v[0]); o[1] = f2bf(v[1]); o[2] = f2bf(v[2]); o[3] = f2bf(v[3]);
    *(us4*)(out + (size_t)i * 4) = o;
  }
}

// 4 weight matrices in one launch (blockIdx.y selects tensor)
__global__ void cvt4_kernel(const float* __restrict__ w0, const float* __restrict__ w1,
                            const float* __restrict__ w2, const float* __restrict__ w3,
                            unsigned short* __restrict__ o0, unsigned short* __restrict__ o1,
                            unsigned short* __restrict__ o2, unsigned short* __restrict__ o3,
                            int n4) {
  const float* in = blockIdx.y == 0 ? w0 : blockIdx.y == 1 ? w1 : blockIdx.y == 2 ? w2 : w3;
  unsigned short* out = blockIdx.y == 0 ? o0 : blockIdx.y == 1 ? o1 : blockIdx.y == 2 ? o2 : o3;
  int i = blockIdx.x * blockDim.x + threadIdx.x;
  int stride = gridDim.x * blockDim.x;
  for (; i < n4; i += stride) {
    float4v v = *(const float4v*)(in + (size_t)i * 4);
    us4 o;
    o[0] = f2bf(v[0]); o[1] = f2bf(v[1]); o[2] = f2bf(v[2]); o[3] = f2bf(v[3]);
    *(us4*)(out + (size_t)i * 4) = o;
  }
}

// MFMA quadrant: C rows [H*64..] x cols [G*128..] of the wave tile, full BK=64.
template<int H, int G>
__device__ __forceinline__ void mfq(f32x4 (&acc)[8][4], const short8* a, const short8* b) {
#pragma unroll
  for (int i2 = 0; i2 < 4; ++i2)
#pragma unroll
    for (int j2 = 0; j2 < 2; ++j2)
#pragma unroll
      for (int kk = 0; kk < 2; ++kk)
        acc[H * 4 + i2][G * 2 + j2] = __builtin_amdgcn_mfma_f32_16x16x32_bf16(
            a[i2 * 2 + kk], b[j2 * 2 + kk], acc[H * 4 + i2][G * 2 + j2], 0, 0, 0);
}

// ---------------- big bf16 GEMM: C[16384,1536] = A[16384,1536] * B[1536,1536]^T ----------------
// 8-phase-style schedule: 256x256 tile, BK=64, 512 threads = 8 waves (2M x 4N),
// wave tile 128x64. 2 LDS dbufs (128 KB). 4 phases per K-tile:
//   ph0: vmcnt(10) BAR | read A-h0(8)+B-g0(4) | stage A-q1(kt+1,buf^1) | lgkm0 | MFMA(h0,g0)
//   ph1: vmcnt(10) BAR | read B-g1(4)          | stage A-q0(kt+2,buf)   | lgkm0 | MFMA(h0,g1)
//   ph2: vmcnt(10) BAR | read A-h1(8)          | stage B-g0(kt+2,buf)   | lgkm0 | MFMA(h1,g1)
//   ph3: (no reads, no barrier)                | stage B-g1(kt+2,buf)           | MFMA(h1,g0)
// Correctness protocol: reads ONLY after the barrier that follows vmcnt(10); stages are
// UNCONDITIONAL (wrapped kt) so per-wave load counts stay uniform -> vmcnt(10) pops exactly
// the producer loads of each phase's reads (5 stage-calls = 10 loads younger). Overwrite
// safety: a region's readers drain (lgkmcnt(0)) before the next barrier; its re-stage is
// issued only after that barrier.
// Swizzle: 16B-granule; LDS[row][g] holds global granule g^(row&7), both sides (involution).
// MODE 0: C bf16.  MODE 1: C fp32 = acc + bias[n] + resid[m,n].
template<int MODE>
__global__ __launch_bounds__(512, 2) void gemm_big(
    const unsigned short* __restrict__ A,
    const unsigned short* __restrict__ B,
    unsigned short* __restrict__ Cb,
    float* __restrict__ Cf,
    const float* __restrict__ bias,
    const float* __restrict__ resid) {
  constexpr int K = 1536, N = 1536, BK = 64, NKT = K / BK;  // 24 K-tiles
  __shared__ unsigned short As[2][256 * 64];   // 64 KB
  __shared__ unsigned short Bs[2][256 * 64];   // 64 KB

  // XCD-chunked swizzle: 384 blocks -> 48/XCD = 8 m-tiles x 6 n-tiles, n fastest
  const int bid = blockIdx.x;
  const int xcd = bid & 7, idx = bid >> 3;
  const int m0 = (xcd * 8 + idx / 6) * 256;
  const int n0 = (idx % 6) * 256;

  const int t = threadIdx.x;
  const int w = t >> 6, l = t & 63, lr = l & 15, lg = l >> 4;
  const int wr = w >> 2, wc = w & 3;            // 2M x 4N wave grid

  // staging consts: each gload_lds covers 8 rows x 128B; lane l -> row +(l>>3), granule l&7
  const int srow = w * 8 + (l >> 3);            // row within 64-row chunk
  const int sgi  = (l & 7) ^ ((l >> 3) & 7);    // pre-swizzled source granule (row&7 == l>>3)
  const int rdsw = lr & 7;                      // read-side swizzle key (row&7 == lr&7)

  f32x4 acc[8][4] = {};

  // stage A quarter q (local rows q*64+[0..63] and q*64+128+[0..63]) of tile kt into dbuf d
  auto stageA = [&](int d, int q, int kt) {
    if (kt >= NKT) kt -= NKT;                   // wrapped dummy stage keeps vmcnt counts uniform
    const unsigned short* src = A + (size_t)(m0 + q * 64 + srow) * K + kt * 64 + sgi * 8;
#pragma unroll
    for (int j = 0; j < 2; ++j)
      __builtin_amdgcn_global_load_lds(GLB_PTR(src + (size_t)j * 128 * K),
          LDS_PTR(&As[d][(q * 64 + j * 128 + w * 8) * 64]), 16, 0, 0);
  };
  // stage B half g (rows r with (r%64) in [g*32, g*32+32)) of tile kt into dbuf d
  auto stageB = [&](int d, int g, int kt) {
    if (kt >= NKT) kt -= NKT;
    const int rb = g * 32 + (w >> 1) * 64 + (w & 1) * 16;
    const unsigned short* src = B + (size_t)(n0 + rb + (l >> 3)) * K + kt * 64 + sgi * 8;
#pragma unroll
    for (int j = 0; j < 2; ++j)
      __builtin_amdgcn_global_load_lds(GLB_PTR(src + (size_t)j * 8 * K),
          LDS_PTR(&Bs[d][(rb + j * 8) * 64]), 16, 0, 0);
  };
  auto readA = [&](int d, int h, short8* a) {
#pragma unroll
    for (int i2 = 0; i2 < 4; ++i2)
#pragma unroll
      for (int kk = 0; kk < 2; ++kk) {
        const int row = wr * 128 + (h * 4 + i2) * 16 + lr;
        const int gi = (kk * 4 + lg) ^ rdsw;
        a[i2 * 2 + kk] = *(const short8*)(&As[d][row * 64 + gi * 8]);
      }
  };
  auto readB = [&](int d, int g, short8* b) {
#pragma unroll
    for (int j2 = 0; j2 < 2; ++j2)
#pragma unroll
      for (int kk = 0; kk < 2; ++kk) {
        const int row = wc * 64 + (g * 2 + j2) * 16 + lr;
        const int gi = (kk * 4 + lg) ^ rdsw;
        b[j2 * 2 + kk] = *(const short8*)(&Bs[d][row * 64 + gi * 8]);
      }
  };

  short8 aCur[8], b0[4], b1[4];

  // prologue issue order (defines producer offsets): A0q0 B0g0 B0g1 A0q1 | A1q0 B1g0 B1g1
  stageA(0, 0, 0); stageB(0, 0, 0); stageB(0, 1, 0); stageA(0, 1, 0);
  stageA(1, 0, 1); stageB(1, 0, 1); stageB(1, 1, 1);

  int d = 0;
  for (int kt = 0; kt < NKT; ++kt, d ^= 1) {
    // ---- phase 0 ----
    asm volatile("s_waitcnt vmcnt(10)" ::: "memory");   // pops A(d)q0 + B(d)g0 producers
    __builtin_amdgcn_s_barrier();                       // => all waves' producers retired
    __builtin_amdgcn_sched_barrier(0);
    readA(d, 0, aCur); readB(d, 0, b0);
    stageA(d ^ 1, 1, kt + 1);
    asm volatile("s_waitcnt lgkmcnt(0)" ::: "memory");
    __builtin_amdgcn_sched_barrier(0);
    __builtin_amdgcn_s_setprio(1); mfq<0, 0>(acc, aCur, b0); __builtin_amdgcn_s_setprio(0);
    // ---- phase 1 ----
    asm volatile("s_waitcnt vmcnt(10)" ::: "memory");   // pops B(d)g1 producer
    __builtin_amdgcn_s_barrier();
    __builtin_amdgcn_sched_barrier(0);
    readB(d, 1, b1);
    stageA(d, 0, kt + 2);
    asm volatile("s_waitcnt lgkmcnt(0)" ::: "memory");
    __builtin_amdgcn_sched_barrier(0);
    __builtin_amdgcn_s_setprio(1); mfq<0, 1>(acc, aCur, b1); __builtin_amdgcn_s_setprio(0);
    // ---- phase 2 ----
    asm volatile("s_waitcnt vmcnt(10)" ::: "memory");   // pops A(d)q1 producer
    __builtin_amdgcn_s_barrier();
    __builtin_amdgcn_sched_barrier(0);
    readA(d, 1, aCur);
    stageB(d, 0, kt + 2);
    asm volatile("s_waitcnt lgkmcnt(0)" ::: "memory");
    __builtin_amdgcn_sched_barrier(0);
    __builtin_amdgcn_s_setprio(1); mfq<1, 1>(acc, aCur, b1); __builtin_amdgcn_s_setprio(0);
    // ---- phase 3 (no reads -> no vmcnt/barrier needed) ----
    stageB(d, 1, kt + 2);
    __builtin_amdgcn_s_setprio(1); mfq<1, 0>(acc, aCur, b0); __builtin_amdgcn_s_setprio(0);
  }

#pragma unroll
  for (int i = 0; i < 8; ++i) {
    const int rb = m0 + wr * 128 + i * 16 + lg * 4;
#pragma unroll
    for (int j = 0; j < 4; ++j) {
      const int col = n0 + wc * 64 + j * 16 + lr;
#pragma unroll
      for (int r = 0; r < 4; ++r) {
        size_t o = (size_t)(rb + r) * N + col;
        if (MODE == 0) Cb[o] = f2bf(acc[i][j][r]);
        else           Cf[o] = acc[i][j][r] + bias[col] + resid[o];
      }
    }
  }
}

// ---------------- K+V projection (small M): 128x128 tile, merged into one launch ----------------
__global__ __launch_bounds__(256) void gemm_kv(
    const unsigned short* __restrict__ A,    // EHSb [616,1536]
    const unsigned short* __restrict__ Bk,
    const unsigned short* __restrict__ Bv,
    unsigned short* __restrict__ Ck,
    unsigned short* __restrict__ Cv) {
  constexpr int K = 1536, N = 1536, Mc = 615;
  __shared__ unsigned short As[128 * 32];
  __shared__ unsigned short Bs[128 * 32];
  const unsigned short* B = blockIdx.y < 12 ? Bk : Bv;
  unsigned short* C = blockIdx.y < 12 ? Ck : Cv;
  const int m0 = blockIdx.x * 128, n0 = (blockIdx.y % 12) * 128;
  const int t = threadIdx.x;
  const int w = t >> 6, l = t & 63, lr = l & 15, lg = l >> 4;
  const int wr = w >> 1, wc = w & 1;
  const int srow = t >> 2, scol = (t & 3) * 8;

  f32x4 acc[4][4] = {};
  unsigned short* AsW = As + w * 512;
  unsigned short* BsW = Bs + w * 512;
  long ar0 = m0 + srow;       if (ar0 > Mc) ar0 = Mc;
  long ar1 = m0 + srow + 64;  if (ar1 > Mc) ar1 = Mc;

  for (int k0 = 0; k0 < K; k0 += 32) {
    __builtin_amdgcn_global_load_lds(GLB_PTR(A + ar0 * (long)K + k0 + scol), LDS_PTR(AsW),        16, 0, 0);
    __builtin_amdgcn_global_load_lds(GLB_PTR(A + ar1 * (long)K + k0 + scol), LDS_PTR(AsW + 2048), 16, 0, 0);
    __builtin_amdgcn_global_load_lds(GLB_PTR(B + (long)(n0 + srow) * K + k0 + scol),      LDS_PTR(BsW),        16, 0, 0);
    __builtin_amdgcn_global_load_lds(GLB_PTR(B + (long)(n0 + srow + 64) * K + k0 + scol), LDS_PTR(BsW + 2048), 16, 0, 0);
    __syncthreads();

    short8 af[4], bfv[4];
#pragma unroll
    for (int i = 0; i < 4; ++i) {
      af[i]  = *(const short8*)(As + (wr * 64 + i * 16 + lr) * 32 + lg * 8);
      bfv[i] = *(const short8*)(Bs + (wc * 64 + i * 16 + lr) * 32 + lg * 8);
    }
#pragma unroll
    for (int i = 0; i < 4; ++i)
#pragma unroll
      for (int j = 0; j < 4; ++j)
        acc[i][j] = __builtin_amdgcn_mfma_f32_16x16x32_bf16(af[i], bfv[j], acc[i][j], 0, 0, 0);
    __syncthreads();
  }

#pragma unroll
  for (int i = 0; i < 4; ++i) {
    int rb = m0 + wr * 64 + i * 16 + lg * 4;
#pragma unroll
    for (int j = 0; j < 4; ++j) {
      int col = n0 + wc * 64 + j * 16 + lr;
#pragma unroll
      for (int r = 0; r < 4; ++r)
        C[(long)(rb + r) * N + col] = f2bf(acc[i][j][r]);
    }
  }
}

// ---------------- V transpose: Vb[(c*154+e), h*64+d] -> Vt[c][h][d][e(160, zero-pad)] ----------------
__global__ void vtrans(const unsigned short* __restrict__ Vb, unsigned short* __restrict__ Vt) {
  int c = blockIdx.x / 24, h = blockIdx.x % 24;
  for (int idx = threadIdx.x; idx < 64 * 160; idx += blockDim.x) {
    int d = idx & 63, e = idx >> 6;
    unsigned short v = 0;
    if (e < 154) v = Vb[(long)(c * 154 + e) * 1536 + h * 64 + d];
    Vt[((long)((c * 24 + h) * 64 + d)) * 160 + e] = v;
  }
}

// ---------------- fused cross-component attention ----------------
__global__ __launch_bounds__(256) void attn_kernel(
    const unsigned short* __restrict__ Qb,   // [4*4096, 1536]
    const unsigned short* __restrict__ Kb,   // [640, 1536]; rows c*154+e
    const unsigned short* __restrict__ Vt,   // [4][24][64][160]
    const float* __restrict__ temp,
    unsigned short* __restrict__ Ob) {       // [4*4096, 1536]
  __shared__ unsigned short P[4][4][16][160];  // [wave][c][s][e] bf16 weights
  const int h = blockIdx.y, sb = blockIdx.x;
  const int t = threadIdx.x, w = t >> 6, l = t & 63, lr = l & 15, lg = l >> 4;
  const int s0 = sb * 64 + w * 16;
  const float sc = 1.0f / (temp[0] + 1e-8f);

  short8 qf[4][2];
#pragma unroll
  for (int c = 0; c < 4; ++c)
#pragma unroll
    for (int kt = 0; kt < 2; ++kt)
      qf[c][kt] = *(const short8*)(Qb + (long)(c * 4096 + s0 + lr) * 1536 + h * 64 + kt * 32 + lg * 8);

  for (int et = 0; et < 10; ++et) {
    f32x4 sa[4] = {};
#pragma unroll
    for (int c = 0; c < 4; ++c)
#pragma unroll
      for (int kt = 0; kt < 2; ++kt) {
        short8 kf = *(const short8*)(Kb + (long)(c * 154 + et * 16 + lr) * 1536 + h * 64 + kt * 32 + lg * 8);
        sa[c] = __builtin_amdgcn_mfma_f32_16x16x32_bf16(kf, qf[c][kt], sa[c], 0, 0, 0);
      }
    float wv[4][4];
#pragma unroll
    for (int r = 0; r < 4; ++r) {
      float x0 = sa[0][r] * sc, x1 = sa[1][r] * sc, x2 = sa[2][r] * sc, x3 = sa[3][r] * sc;
      float m = fmaxf(fmaxf(x0, x1), fmaxf(x2, x3));
      float e0 = __expf(x0 - m), e1 = __expf(x1 - m), e2 = __expf(x2 - m), e3 = __expf(x3 - m);
      float inv = 1.0f / (e0 + e1 + e2 + e3);
      wv[0][r] = e0 * inv; wv[1][r] = e1 * inv; wv[2][r] = e2 * inv; wv[3][r] = e3 * inv;
    }
#pragma unroll
    for (int c = 0; c < 4; ++c) {
      us4 pk;
      pk[0] = f2bf(wv[c][0]); pk[1] = f2bf(wv[c][1]); pk[2] = f2bf(wv[c][2]); pk[3] = f2bf(wv[c][3]);
      *(us4*)&P[w][c][lr][et * 16 + lg * 4] = pk;
    }
  }
  __syncthreads();

  f32x4 o[4][4] = {};
#pragma unroll
  for (int c = 0; c < 4; ++c)
    for (int ks = 0; ks < 5; ++ks) {
      short8 pf = *(const short8*)&P[w][c][lr][ks * 32 + lg * 8];
#pragma unroll
      for (int nt = 0; nt < 4; ++nt) {
        short8 vf = *(const short8*)(Vt + (long)((c * 24 + h) * 64 + nt * 16 + lr) * 160 + ks * 32 + lg * 8);
        o[c][nt] = __builtin_amdgcn_mfma_f32_16x16x32_bf16(pf, vf, o[c][nt], 0, 0, 0);
      }
    }

#pragma unroll
  for (int c = 0; c < 4; ++c)
#pragma unroll
    for (int nt = 0; nt < 4; ++nt)
#pragma unroll
      for (int r = 0; r < 4; ++r)
        Ob[(long)(c * 4096 + s0 + lg * 4 + r) * 1536 + h * 64 + nt * 16 + lr] = f2bf(o[c][nt][r]);
}

extern "C" void kernel_launch(void* const* d_in, const int* in_sizes, int n_in,
                              void* d_out, int out_size, void* d_ws, size_t ws_size,
                              hipStream_t stream) {
  (void)in_sizes; (void)n_in; (void)out_size; (void)ws_size;
  const float* HS  = (const float*)d_in[0];
  const float* EHS = (const float*)d_in[1];
  const float* TMP = (const float*)d_in[2];
  const float* Wq  = (const float*)d_in[3];
  const float* Wk  = (const float*)d_in[4];
  const float* Wv  = (const float*)d_in[5];
  const float* Wo  = (const float*)d_in[6];
  const float* bo  = (const float*)d_in[7];

  char* ws = (char*)d_ws;
  size_t off = 0;
  unsigned short* HSb  = (unsigned short*)(ws + off); off += (size_t)16384 * 1536 * 2;  // reused as Ob
  unsigned short* Ob   = HSb;
  unsigned short* EHSb = (unsigned short*)(ws + off); off += (size_t)616 * 1536 * 2;
  unsigned short* Wqb  = (unsigned short*)(ws + off); off += (size_t)1536 * 1536 * 2;
  unsigned short* Wkb  = (unsigned short*)(ws + off); off += (size_t)1536 * 1536 * 2;
  unsigned short* Wvb  = (unsigned short*)(ws + off); off += (size_t)1536 * 1536 * 2;
  unsigned short* Wob  = (unsigned short*)(ws + off); off += (size_t)1536 * 1536 * 2;
  unsigned short* Kb   = (unsigned short*)(ws + off); off += (size_t)640 * 1536 * 2;
  unsigned short* Vb   = (unsigned short*)(ws + off); off += (size_t)640 * 1536 * 2;
  unsigned short* Vt   = (unsigned short*)(ws + off); off += (size_t)4 * 24 * 64 * 160 * 2;
  unsigned short* Qb   = (unsigned short*)d_out;  // bf16 scratch; final GEMM overwrites d_out fully

  cvt_kernel<<<2048, 256, 0, stream>>>(HS,  HSb,  16384 * 1536 / 4);
  cvt_kernel<<<512,  256, 0, stream>>>(EHS, EHSb, 616 * 1536 / 4);
  cvt4_kernel<<<dim3(576, 4), 256, 0, stream>>>(Wq, Wk, Wv, Wo, Wqb, Wkb, Wvb, Wob, 1536 * 1536 / 4);

  gemm_big<0><<<384, 512, 0, stream>>>(HSb, Wqb, Qb, nullptr, nullptr, nullptr);
  gemm_kv<<<dim3(5, 24), 256, 0, stream>>>(EHSb, Wkb, Wvb, Kb, Vb);

  vtrans<<<96, 256, 0, stream>>>(Vb, Vt);

  attn_kernel<<<dim3(64, 24), 256, 0, stream>>>(Qb, Kb, Vt, TMP, Ob);

  gemm_big<1><<<384, 512, 0, stream>>>(Ob, Wob, nullptr, (float*)d_out, bo, HS);
}